// Round 15
// baseline (221.255 us; speedup 1.0000x reference)
//
#include <hip/hip_runtime.h>
#include <math.h>

#define NT 32768
#define DIM 2048
#define NE 64
#define RSCALE 2.5f
#define REPS 1e-20f
#define KC 32
#define NCH (DIM / KC)
#define TOKB 32

// per-wave LDS: 2 bufs x 3 limbs x 1024 B = 6144; 4 waves = 24576; bsf after.
// Sc f32[32][65] (8320 B) aliases wave buffers in the epilogue (barrier-guarded).
#define WAVE_LDS 6144
#define BUF_STRIDE 3072
#define BS_OFF 24576
#define ARENA 24832

typedef const __attribute__((address_space(1))) void GV;
typedef __attribute__((address_space(3))) void LV;
typedef __attribute__((ext_vector_type(8))) short short8x;
typedef __attribute__((ext_vector_type(4))) float f32x4;
typedef __attribute__((ext_vector_type(4))) unsigned int uint4x;

// W limb image, pre-decomposed + pre-swizzled (byte-identical to the LDS content the
// R9/R14 kernels staged). 768 KB, L2-resident.
__device__ __align__(16) char WImg[NCH][3 * 4096];

#define PACKHI(odd, even) __builtin_amdgcn_perm((odd), (even), 0x07060302u)

__device__ __forceinline__ void decomp4(f32x4 x, unsigned int o[6]) {
    unsigned int u0 = __float_as_uint(x.x), u1 = __float_as_uint(x.y);
    unsigned int u2 = __float_as_uint(x.z), u3 = __float_as_uint(x.w);
    o[0] = PACKHI(u1, u0); o[1] = PACKHI(u3, u2);
    float r0 = x.x - __uint_as_float(u0 & 0xffff0000u);
    float r1 = x.y - __uint_as_float(u1 & 0xffff0000u);
    float r2 = x.z - __uint_as_float(u2 & 0xffff0000u);
    float r3 = x.w - __uint_as_float(u3 & 0xffff0000u);
    unsigned int v0 = __float_as_uint(r0), v1 = __float_as_uint(r1);
    unsigned int v2 = __float_as_uint(r2), v3 = __float_as_uint(r3);
    o[2] = PACKHI(v1, v0); o[3] = PACKHI(v3, v2);
    float s0 = r0 - __uint_as_float(v0 & 0xffff0000u);
    float s1 = r1 - __uint_as_float(v1 & 0xffff0000u);
    float s2 = r2 - __uint_as_float(v2 & 0xffff0000u);
    float s3 = r3 - __uint_as_float(v3 & 0xffff0000u);
    o[4] = PACKHI(__float_as_uint(s1), __float_as_uint(s0));
    o[5] = PACKHI(__float_as_uint(s3), __float_as_uint(s2));
}

__device__ __forceinline__ void decomp8(f32x4 a, f32x4 b,
                                        short8x* f0, short8x* f1, short8x* f2) {
    unsigned int oa[6], ob[6];
    decomp4(a, oa); decomp4(b, ob);
    uint4x t0 = {oa[0], oa[1], ob[0], ob[1]};
    uint4x t1 = {oa[2], oa[3], ob[2], ob[3]};
    uint4x t2 = {oa[4], oa[5], ob[4], ob[5]};
    *f0 = __builtin_bit_cast(short8x, t0);
    *f1 = __builtin_bit_cast(short8x, t1);
    *f2 = __builtin_bit_cast(short8x, t2);
}

// pre-pass: decompose W once into the image layout. 64 blocks x 256. (R14-verified)
__global__ void prep_w_kernel(const float* __restrict__ W) {
    const int ch = blockIdx.x;
    const int tid = threadIdx.x;
    const int srow = tid >> 2;          // expert row 0..63
    const int sq   = tid & 3;           // k-octet 0..3
    const float* src = W + (size_t)srow * DIM + ch * KC + sq * 8;
    f32x4 lo = *(const f32x4*)src;
    f32x4 hi = *(const f32x4*)(src + 4);
    short8x f0, f1, f2;
    decomp8(lo, hi, &f0, &f1, &f2);
    const int soff = srow * 64 + ((sq ^ ((srow >> 1) & 3)) << 4);
    *(short8x*)&WImg[ch][0 * 4096 + soff] = f0;
    *(short8x*)&WImg[ch][1 * 4096 + soff] = f1;
    *(short8x*)&WImg[ch][2 * 4096 + soff] = f2;
}

#define SB __builtin_amdgcn_sched_barrier(0)

// wave-local counted wait: previous chunk's 7 vmem ops (4 H + 3 DMA) complete,
// this chunk's 7 stay in flight. No block barrier anywhere in the main loop.
#define VWAIT() do { SB; asm volatile("s_waitcnt vmcnt(7)" ::: "memory"); SB; } while (0)

// issue A loads for chunk CHN (2 token-tiles, f32x8 each as 2x f32x4) -- H FIRST
#define HSTAGE(R0, R1, R2, R3, CHN) do { \
    const float* p0_ = hg0 + (CHN) * KC; \
    const float* p1_ = hg1 + (CHN) * KC; \
    R0 = *(const f32x4*)p0_; R1 = *(const f32x4*)(p0_ + 4); \
    R2 = *(const f32x4*)p1_; R3 = *(const f32x4*)(p1_ + 4); \
} while (0)

// wave-private W DMA: 3 x 1 KB contiguous (16 experts x 64 B per limb)
#define WSTAGE(CHN, BUFB) do { \
    const char* ws_ = WImg[(CHN)]; \
    __builtin_amdgcn_global_load_lds((GV*)(ws_ + 0 * 4096 + wimg_off), \
        (LV*)(warena + (BUFB) + 0 * 1024), 16, 0, 0); \
    __builtin_amdgcn_global_load_lds((GV*)(ws_ + 1 * 4096 + wimg_off), \
        (LV*)(warena + (BUFB) + 1 * 1024), 16, 0, 0); \
    __builtin_amdgcn_global_load_lds((GV*)(ws_ + 2 * 4096 + wimg_off), \
        (LV*)(warena + (BUFB) + 2 * 1024), 16, 0, 0); \
} while (0)

// wave = 32 tok x 16 exp = 2 tiles; A decomposed in-register (same bits as LDS-staged),
// B via 3 ds_read_b128. Per-(t,e) limb-product order identical to passing kernels.
#define COMPUTE(BUFB, R0, R1, R2, R3) do { \
    short8x a0[2], a1[2], a2[2]; \
    decomp8(R0, R1, &a0[0], &a1[0], &a2[0]); \
    decomp8(R2, R3, &a0[1], &a1[1], &a2[1]); \
    const char* wb_ = warena + (BUFB); \
    short8x b0 = *(const short8x*)(wb_ + 0 * 1024 + bo); \
    short8x b1 = *(const short8x*)(wb_ + 1 * 1024 + bo); \
    short8x b2 = *(const short8x*)(wb_ + 2 * 1024 + bo); \
    _Pragma("unroll") \
    for (int tt = 0; tt < 2; ++tt) { \
        Cm[tt] = __builtin_amdgcn_mfma_f32_16x16x32_bf16(a0[tt], b0, Cm[tt], 0, 0, 0); \
        Cc[tt] = __builtin_amdgcn_mfma_f32_16x16x32_bf16(a1[tt], b0, Cc[tt], 0, 0, 0); \
        Cc[tt] = __builtin_amdgcn_mfma_f32_16x16x32_bf16(a2[tt], b0, Cc[tt], 0, 0, 0); \
        Cc[tt] = __builtin_amdgcn_mfma_f32_16x16x32_bf16(a0[tt], b1, Cc[tt], 0, 0, 0); \
        Cc[tt] = __builtin_amdgcn_mfma_f32_16x16x32_bf16(a1[tt], b1, Cc[tt], 0, 0, 0); \
        Cc[tt] = __builtin_amdgcn_mfma_f32_16x16x32_bf16(a0[tt], b2, Cc[tt], 0, 0, 0); \
    } \
} while (0)

#define DRAIN do { \
    _Pragma("unroll") \
    for (int tt = 0; tt < 2; ++tt) { \
        _Pragma("unroll") \
        for (int r = 0; r < 4; ++r) \
            md[tt][r] += (double)Cm[tt][r] + (double)Cc[tt][r]; \
        Cm[tt] = (f32x4)0.0f; Cc[tt] = (f32x4)0.0f; \
    } \
} while (0)

// 1024 blocks x 256 threads (4 waves). Block = 32 tok; wave w = experts w*16..w*16+15
// x all 32 tokens x full K. Barrier-free main loop, wave-private dbuf LDS, counted
// vmcnt(7). 4 blocks/CU = 16 waves/CU. fp64 drain windows / MFMA order bit-identical.
__global__ __launch_bounds__(256, 4) void router_kernel(
    const float* __restrict__ H,
    const float* __restrict__ B,
    float* __restrict__ out)
{
    __shared__ __align__(16) char arena[ARENA];
    float* bsf = (float*)(arena + BS_OFF);
    float* scf = (float*)(arena);                 // epilogue alias over wave buffers

    const int tid  = threadIdx.x;
    const int lane = tid & 63;
    const int w    = __builtin_amdgcn_readfirstlane(tid >> 6);
    const int l15  = lane & 15, g = lane >> 4;
    const size_t tb = (size_t)blockIdx.x * TOKB;

    float breg = (tid < NE) ? B[tid] : 0.0f;

    char* warena = arena + w * WAVE_LDS;
    const int wimg_off = w * 1024 + lane * 16;    // per-lane global src offset
    const float* hg0 = H + (tb + (size_t)l15) * DIM + g * 8;
    const float* hg1 = H + (tb + 16 + (size_t)l15) * DIM + g * 8;
    const int bo = l15 * 64 + ((g ^ ((l15 >> 1) & 3)) << 4);

    f32x4 Cm[2], Cc[2];
    double md[2][4];
    #pragma unroll
    for (int tt = 0; tt < 2; ++tt) {
        Cm[tt] = (f32x4)0.0f; Cc[tt] = (f32x4)0.0f;
        #pragma unroll
        for (int r = 0; r < 4; ++r) md[tt][r] = 0.0;
    }

    f32x4 hA0, hA1, hA2, hA3, hB0, hB1, hB2, hB3;

    // prologue: chunk 0 -> regs + buf0
    HSTAGE(hA0, hA1, hA2, hA3, 0);
    WSTAGE(0, 0);

    for (int chb = 0; chb < NCH; chb += 2) {
        const int c1 = chb + 1;
        const int c2 = (chb + 2 < NCH) ? chb + 2 : NCH - 1;   // clamped (count constant)

        // chunk chb: issue chb+1, wait for chb, compute
        HSTAGE(hB0, hB1, hB2, hB3, c1);
        WSTAGE(c1, BUF_STRIDE);
        VWAIT();
        COMPUTE(0, hA0, hA1, hA2, hA3);

        // chunk chb+1: issue chb+2, wait for chb+1, compute
        HSTAGE(hA0, hA1, hA2, hA3, c2);
        WSTAGE(c2, 0);
        VWAIT();
        COMPUTE(BUF_STRIDE, hB0, hB1, hB2, hB3);
        if (((chb + 1) & 7) == 7) DRAIN;          // global chunks 7,15,...,63
    }

    if (tid < NE) bsf[tid] = breg;
    __syncthreads();      // all waves done with buffers (drains dangling vmcnt too)

    // sigmoid scores -> Sc (aliases wave buffers)
    #pragma unroll
    for (int tt = 0; tt < 2; ++tt)
        #pragma unroll
        for (int r = 0; r < 4; ++r) {
            float logit = (float)md[tt][r];
            float s = 1.0f / (1.0f + expf(-logit));
            int t = tt * 16 + g * 4 + r;
            int e = w * 16 + l15;
            scf[t * 65 + e] = s;
        }
    __syncthreads();

    // grouped top-k, one token per active thread (32 tokens over 4 waves)
    if ((tid & 7) == 0) {
        const int t = tid >> 3;
        const float* sc = &scf[t * 65];
        float gs[8];
        #pragma unroll
        for (int gg = 0; gg < 8; ++gg) {
            float m1 = -1e30f, m2 = -1e30f;
            #pragma unroll
            for (int j = 0; j < 8; ++j) {
                float v = sc[gg * 8 + j] + bsf[gg * 8 + j];
                if (v > m1) { m2 = m1; m1 = v; }
                else if (v > m2) { m2 = v; }
            }
            gs[gg] = m1 + m2;
        }
        unsigned gmask = 0;
        for (int i = 0; i < 4; ++i) {
            float best = -1e30f; int bg = 0;
            for (int gg = 0; gg < 8; ++gg)
                if (!((gmask >> gg) & 1u) && gs[gg] > best) { best = gs[gg]; bg = gg; }
            gmask |= 1u << bg;
        }
        unsigned long long picked = 0ull;
        int   idxs[8];
        float wts[8];
        float wsum = 0.0f;
        for (int i = 0; i < 8; ++i) {
            float best = -1e30f; int bi = 0;
            for (int e = 0; e < 64; ++e) {
                if ((picked >> e) & 1ull) continue;
                float v = ((gmask >> (e >> 3)) & 1u) ? (sc[e] + bsf[e]) : 0.0f;
                if (v > best) { best = v; bi = e; }
            }
            picked |= 1ull << bi;
            idxs[i] = bi;
            wts[i] = sc[bi];
            wsum += sc[bi];
        }
        const float scale = RSCALE / (wsum + REPS);
        const size_t token = tb + t;
        #pragma unroll
        for (int i = 0; i < 8; ++i) {
            out[token * 8 + i] = (float)idxs[i];
            out[(size_t)NT * 8 + token * 8 + i] = wts[i] * scale;
        }
    }
}

extern "C" void kernel_launch(void* const* d_in, const int* in_sizes, int n_in,
                              void* d_out, int out_size, void* d_ws, size_t ws_size,
                              hipStream_t stream) {
    (void)in_sizes; (void)n_in; (void)out_size; (void)d_ws; (void)ws_size;
    const float* H = (const float*)d_in[0];
    const float* W = (const float*)d_in[1];
    const float* B = (const float*)d_in[2];
    float* out = (float*)d_out;
    prep_w_kernel<<<dim3(NCH), dim3(256), 0, stream>>>(W);
    router_kernel<<<dim3(NT / TOKB), dim3(256), 0, stream>>>(H, B, out);
}

// Round 16
// 143.267 us; speedup vs baseline: 1.5444x; 1.5444x over previous
//
#include <hip/hip_runtime.h>
#include <math.h>

#define NT 32768
#define DIM 2048
#define NE 64
#define RSCALE 2.5f
#define REPS 1e-20f
#define KC 32
#define NCH (DIM / KC)
#define TOK 32

// LDS arena (bytes):
//   HL[2][3][32 tok][4 slots x 16B] : 0     .. 12287   (H limb planes, dbuf; 6144/buf)
//   WL[2][3][64 exp][4 slots x 16B] : 12288 .. 36863   (W limb planes, dbuf; 12288/buf)
//   Bs[64] f32                      : 36864 .. 37119
//   Sc[32][65] f32                  : alias at 0 (epilogue only, 8320 B)
#define HL_BUF 6144
#define WL_OFF 12288
#define WL_BUF 12288
#define BS_OFF 36864
#define ARENA 37120

typedef const __attribute__((address_space(1))) void GV;
typedef __attribute__((address_space(3))) void LV;
typedef __attribute__((ext_vector_type(8))) short short8x;
typedef __attribute__((ext_vector_type(4))) float f32x4;
typedef __attribute__((ext_vector_type(4))) unsigned int uint4x;

// W limb image, pre-decomposed + pre-swizzled (byte-identical to the LDS bytes the
// passing kernels staged). 768 KB, L2-resident. (R14-verified)
__device__ __align__(16) char WImg[NCH][3 * 4096];

#define PACKHI(odd, even) __builtin_amdgcn_perm((odd), (even), 0x07060302u)

__device__ __forceinline__ void decomp4(f32x4 x, unsigned int o[6]) {
    unsigned int u0 = __float_as_uint(x.x), u1 = __float_as_uint(x.y);
    unsigned int u2 = __float_as_uint(x.z), u3 = __float_as_uint(x.w);
    o[0] = PACKHI(u1, u0); o[1] = PACKHI(u3, u2);
    float r0 = x.x - __uint_as_float(u0 & 0xffff0000u);
    float r1 = x.y - __uint_as_float(u1 & 0xffff0000u);
    float r2 = x.z - __uint_as_float(u2 & 0xffff0000u);
    float r3 = x.w - __uint_as_float(u3 & 0xffff0000u);
    unsigned int v0 = __float_as_uint(r0), v1 = __float_as_uint(r1);
    unsigned int v2 = __float_as_uint(r2), v3 = __float_as_uint(r3);
    o[2] = PACKHI(v1, v0); o[3] = PACKHI(v3, v2);
    float s0 = r0 - __uint_as_float(v0 & 0xffff0000u);
    float s1 = r1 - __uint_as_float(v1 & 0xffff0000u);
    float s2 = r2 - __uint_as_float(v2 & 0xffff0000u);
    float s3 = r3 - __uint_as_float(v3 & 0xffff0000u);
    o[4] = PACKHI(__float_as_uint(s1), __float_as_uint(s0));
    o[5] = PACKHI(__float_as_uint(s3), __float_as_uint(s2));
}

__device__ __forceinline__ void decomp8(f32x4 a, f32x4 b,
                                        short8x* f0, short8x* f1, short8x* f2) {
    unsigned int oa[6], ob[6];
    decomp4(a, oa); decomp4(b, ob);
    uint4x t0 = {oa[0], oa[1], ob[0], ob[1]};
    uint4x t1 = {oa[2], oa[3], ob[2], ob[3]};
    uint4x t2 = {oa[4], oa[5], ob[4], ob[5]};
    *f0 = __builtin_bit_cast(short8x, t0);
    *f1 = __builtin_bit_cast(short8x, t1);
    *f2 = __builtin_bit_cast(short8x, t2);
}

// pre-pass: decompose W once into the image layout. 64 blocks x 256. (R14-verified)
__global__ void prep_w_kernel(const float* __restrict__ W) {
    const int ch = blockIdx.x;
    const int tid = threadIdx.x;
    const int srow = tid >> 2;          // expert row 0..63
    const int sq   = tid & 3;           // k-octet 0..3
    const float* src = W + (size_t)srow * DIM + ch * KC + sq * 8;
    f32x4 lo = *(const f32x4*)src;
    f32x4 hi = *(const f32x4*)(src + 4);
    short8x f0, f1, f2;
    decomp8(lo, hi, &f0, &f1, &f2);
    const int soff = srow * 64 + ((sq ^ ((srow >> 1) & 3)) << 4);
    *(short8x*)&WImg[ch][0 * 4096 + soff] = f0;
    *(short8x*)&WImg[ch][1 * 4096 + soff] = f1;
    *(short8x*)&WImg[ch][2 * 4096 + soff] = f2;
}

// H-only register staging (depth-2); threads 0-127 own (row 0..31) x (octet 0..3)
#define STAGE_ISSUE(HA, HB, KOFF) do { \
    if (hact) { \
        HA = *(const f32x4*)(hgsrc + (KOFF)); \
        HB = *(const f32x4*)(hgsrc + (KOFF) + 4); \
    } \
} while (0)

#define STAGE_WRITE_H(HA, HB, PN) do { \
    if (hact) { \
        short8x f0_, f1_, f2_; \
        decomp8(HA, HB, &f0_, &f1_, &f2_); \
        *(short8x*)(arena + (PN) * HL_BUF + 0 * 2048 + soff) = f0_; \
        *(short8x*)(arena + (PN) * HL_BUF + 1 * 2048 + soff) = f1_; \
        *(short8x*)(arena + (PN) * HL_BUF + 2 * 2048 + soff) = f2_; \
    } \
} while (0)

// W staging: L2 -> LDS DMA of the pre-baked image (zero VALU, zero ds_write).
#define WSTAGE(CHN, PN) do { \
    const char* ws_ = WImg[(CHN)]; \
    __builtin_amdgcn_global_load_lds((GV*)(ws_ + 0 * 4096 + wgofs), \
        (LV*)(arena + WL_OFF + (PN) * WL_BUF + 0 * 4096 + wlofs), 16, 0, 0); \
    __builtin_amdgcn_global_load_lds((GV*)(ws_ + 1 * 4096 + wgofs), \
        (LV*)(arena + WL_OFF + (PN) * WL_BUF + 1 * 4096 + wlofs), 16, 0, 0); \
    __builtin_amdgcn_global_load_lds((GV*)(ws_ + 2 * 4096 + wgofs), \
        (LV*)(arena + WL_OFF + (PN) * WL_BUF + 2 * 4096 + wlofs), 16, 0, 0); \
} while (0)

// wave = 16 tok x 32 exp = 1x2 of 16x16 tiles; 9 b128 reads feed 12 MFMAs.
// Per-(t,e) limb-product order identical to the passing kernels (bit-identical logits).
#define COMPUTE(P) do { \
    const char* hb = arena + (P) * HL_BUF; \
    const char* wb = arena + WL_OFF + (P) * WL_BUF; \
    short8x a0, a1, a2; \
    { const int t_ = wr * 16 + l15; \
      const int ro_ = t_ * 64 + ((g ^ ((t_ >> 1) & 3)) << 4); \
      a0 = *(const short8x*)(hb + 0 * 2048 + ro_); \
      a1 = *(const short8x*)(hb + 1 * 2048 + ro_); \
      a2 = *(const short8x*)(hb + 2 * 2048 + ro_); } \
    _Pragma("unroll") \
    for (int et = 0; et < 2; ++et) { \
        const int e_ = wc * 32 + et * 16 + l15; \
        const int ro_ = e_ * 64 + ((g ^ ((e_ >> 1) & 3)) << 4); \
        short8x b0 = *(const short8x*)(wb + 0 * 4096 + ro_); \
        short8x b1 = *(const short8x*)(wb + 1 * 4096 + ro_); \
        short8x b2 = *(const short8x*)(wb + 2 * 4096 + ro_); \
        Cm[et] = __builtin_amdgcn_mfma_f32_16x16x32_bf16(a0, b0, Cm[et], 0, 0, 0); \
        Cc[et] = __builtin_amdgcn_mfma_f32_16x16x32_bf16(a1, b0, Cc[et], 0, 0, 0); \
        Cc[et] = __builtin_amdgcn_mfma_f32_16x16x32_bf16(a2, b0, Cc[et], 0, 0, 0); \
        Cc[et] = __builtin_amdgcn_mfma_f32_16x16x32_bf16(a0, b1, Cc[et], 0, 0, 0); \
        Cc[et] = __builtin_amdgcn_mfma_f32_16x16x32_bf16(a1, b1, Cc[et], 0, 0, 0); \
        Cc[et] = __builtin_amdgcn_mfma_f32_16x16x32_bf16(a0, b2, Cc[et], 0, 0, 0); \
    } \
} while (0)

#define DRAIN do { \
    _Pragma("unroll") \
    for (int et = 0; et < 2; ++et) { \
        _Pragma("unroll") \
        for (int r = 0; r < 4; ++r) \
            md[et][r] += (double)Cm[et][r] + (double)Cc[et][r]; \
        Cm[et] = (f32x4)0.0f; Cc[et] = (f32x4)0.0f; \
    } \
} while (0)

// 1024 blocks x 256 threads (4 waves). Block = 32 tok x 64 exp; wave w: token-tile
// w&1, expert-half w>>1. R14 structure (W-image DMA + H reg staging + dbuf + one
// barrier per chunk) at half tile -> 37 KB LDS -> 4 blocks/CU, 16 waves/CU.
__global__ __launch_bounds__(256, 4) void router_kernel(
    const float* __restrict__ H,
    const float* __restrict__ B,
    float* __restrict__ out)
{
    __shared__ __align__(16) char arena[ARENA];
    float* bsf = (float*)(arena + BS_OFF);
    float* scf = (float*)(arena);

    const int tid  = threadIdx.x;
    const int lane = tid & 63;
    const int w    = __builtin_amdgcn_readfirstlane(tid >> 6);
    const int l15  = lane & 15, g = lane >> 4;
    const size_t tb = (size_t)blockIdx.x * TOK;

    if (tid < NE) bsf[tid] = B[tid];

    // H staging role: threads 0-127: token row = tid>>2 (0..31), k-octet = tid&3
    const bool hact = tid < 128;
    const int srow = tid >> 2;
    const int sq   = tid & 3;
    const float* hgsrc = H + (tb + (size_t)(hact ? srow : 0)) * DIM + sq * 8;
    const int soff = srow * 64 + ((sq ^ ((srow >> 1) & 3)) << 4);

    // W staging addresses: per-lane global offset, wave-uniform LDS offset
    const int wgofs = tid * 16;
    const int wlofs = w * 1024;

    // compute role: wave = token-tile (w&1) x expert-half (w>>1)
    const int wr = w & 1, wc = w >> 1;

    f32x4 Cm[2], Cc[2];
    double md[2][4];
    #pragma unroll
    for (int et = 0; et < 2; ++et) {
        Cm[et] = (f32x4)0.0f; Cc[et] = (f32x4)0.0f;
        #pragma unroll
        for (int r = 0; r < 4; ++r) md[et][r] = 0.0;
    }

    f32x4 hA0, hA1, hB0, hB1;

    // prologue: W ch0 -> buf0 (DMA); H ch0 regs -> write buf0; H ch1 regs
    WSTAGE(0, 0);
    STAGE_ISSUE(hA0, hA1, 0);
    STAGE_WRITE_H(hA0, hA1, 0);
    STAGE_ISSUE(hB0, hB1, KC);
    __syncthreads();

    for (int chb = 0; chb < NCH; chb += 2) {
        // even chunk chb: read buf0; stage ch+1 -> buf1
        WSTAGE(chb + 1, 1);
        if (chb + 2 < NCH) STAGE_ISSUE(hA0, hA1, (chb + 2) * KC);
        COMPUTE(0);
        STAGE_WRITE_H(hB0, hB1, 1);
        __syncthreads();

        // odd chunk chb+1: read buf1; stage ch+2 -> buf0
        if (chb + 2 < NCH) {
            WSTAGE(chb + 2, 0);
            STAGE_ISSUE(hB0, hB1, (chb + 3 < NCH) ? (chb + 3) * KC : (chb + 2) * KC);
        }
        COMPUTE(1);
        if (chb + 2 < NCH) STAGE_WRITE_H(hA0, hA1, 0);
        if (((chb + 1) & 7) == 7) DRAIN;
        __syncthreads();
    }

    // sigmoid scores -> Sc (aliases dead limb planes; all reads done at last barrier)
    #pragma unroll
    for (int et = 0; et < 2; ++et)
        #pragma unroll
        for (int r = 0; r < 4; ++r) {
            float logit = (float)md[et][r];
            float s = 1.0f / (1.0f + expf(-logit));
            int t = wr * 16 + g * 4 + r;
            int e = wc * 32 + et * 16 + l15;
            scf[t * 65 + e] = s;
        }
    __syncthreads();

    // grouped top-k, one token per active thread (32 tokens over 4 waves)
    if ((tid & 7) == 0) {
        const int t = tid >> 3;
        const float* sc = &scf[t * 65];
        float gs[8];
        #pragma unroll
        for (int gg = 0; gg < 8; ++gg) {
            float m1 = -1e30f, m2 = -1e30f;
            #pragma unroll
            for (int j = 0; j < 8; ++j) {
                float v = sc[gg * 8 + j] + bsf[gg * 8 + j];
                if (v > m1) { m2 = m1; m1 = v; }
                else if (v > m2) { m2 = v; }
            }
            gs[gg] = m1 + m2;
        }
        unsigned gmask = 0;
        for (int i = 0; i < 4; ++i) {
            float best = -1e30f; int bg = 0;
            for (int gg = 0; gg < 8; ++gg)
                if (!((gmask >> gg) & 1u) && gs[gg] > best) { best = gs[gg]; bg = gg; }
            gmask |= 1u << bg;
        }
        unsigned long long picked = 0ull;
        int   idxs[8];
        float wts[8];
        float wsum = 0.0f;
        for (int i = 0; i < 8; ++i) {
            float best = -1e30f; int bi = 0;
            for (int e = 0; e < 64; ++e) {
                if ((picked >> e) & 1ull) continue;
                float v = ((gmask >> (e >> 3)) & 1u) ? (sc[e] + bsf[e]) : 0.0f;
                if (v > best) { best = v; bi = e; }
            }
            picked |= 1ull << bi;
            idxs[i] = bi;
            wts[i] = sc[bi];
            wsum += sc[bi];
        }
        const float scale = RSCALE / (wsum + REPS);
        const size_t token = tb + t;
        #pragma unroll
        for (int i = 0; i < 8; ++i) {
            out[token * 8 + i] = (float)idxs[i];
            out[(size_t)NT * 8 + token * 8 + i] = wts[i] * scale;
        }
    }
}

extern "C" void kernel_launch(void* const* d_in, const int* in_sizes, int n_in,
                              void* d_out, int out_size, void* d_ws, size_t ws_size,
                              hipStream_t stream) {
    (void)in_sizes; (void)n_in; (void)out_size; (void)d_ws; (void)ws_size;
    const float* H = (const float*)d_in[0];
    const float* W = (const float*)d_in[1];
    const float* B = (const float*)d_in[2];
    float* out = (float*)d_out;
    prep_w_kernel<<<dim3(NCH), dim3(256), 0, stream>>>(W);
    router_kernel<<<dim3(NT / TOK), dim3(256), 0, stream>>>(H, B, out);
}